// Round 1
// baseline (1449.678 us; speedup 1.0000x reference)
//
#include <hip/hip_runtime.h>
#include <hip/hip_bf16.h>

#define N_NODESC 50000
#define N_EDGESC 800000
#define N_GRAPHSC 512
#define HDIM 64
#define FNODE 32
#define FEDGE 8
#define NCLS 10
#define BN_EPS 1e-5f

static __device__ __forceinline__ float bcast(float v, int k) {
  return __uint_as_float(__builtin_amdgcn_readlane(__float_as_uint(v), k));
}

// ---------------- degree / norm ----------------
__global__ void k_deg(const int* __restrict__ dst, float* __restrict__ deg) {
  int e = blockIdx.x * blockDim.x + threadIdx.x;
  if (e < N_EDGESC) atomicAdd(&deg[dst[e]], 1.0f);
}

__global__ void k_dinv(float* __restrict__ deg) {
  int n = blockIdx.x * blockDim.x + threadIdx.x;
  if (n < N_NODESC) {
    float d = deg[n];
    deg[n] = rsqrtf(fmaxf(d, 1.0f));
  }
}

// ---------------- column stats (sum, sumsq) ----------------
template <int C>
__global__ void k_colstats(const float* __restrict__ in, int nrows, float* __restrict__ stats) {
  const int RPB = 256 / C;
  int tid = threadIdx.x;
  int col = tid % C;
  int rowOff = tid / C;
  float s = 0.f, s2 = 0.f;
  for (int r = blockIdx.x * RPB + rowOff; r < nrows; r += gridDim.x * RPB) {
    float v = in[r * C + col];
    s += v; s2 += v * v;
  }
  __shared__ float ls[256], ls2[256];
  ls[tid] = s; ls2[tid] = s2;
  __syncthreads();
  for (int off = 128; off >= C; off >>= 1) {
    if (tid < off) { ls[tid] += ls[tid + off]; ls2[tid] += ls2[tid + off]; }
    __syncthreads();
  }
  if (tid < C) {
    atomicAdd(&stats[tid], ls[tid]);
    atomicAdd(&stats[C + tid], ls2[tid]);
  }
}

// ---------------- fold BN into weights: Wf = a.*W, bf = sh@W + bias ----------------
template <int CIN, int COUT>
__global__ void k_foldbn(const float* __restrict__ stats, float invN,
                         const float* __restrict__ bnw, const float* __restrict__ bnb,
                         const float* __restrict__ W, const float* __restrict__ bias,
                         float* __restrict__ Wf, float* __restrict__ bf) {
  __shared__ float a[CIN], sh[CIN];
  int tid = threadIdx.x;
  if (tid < CIN) {
    float m = stats[tid] * invN;
    float v = stats[CIN + tid] * invN - m * m;
    float inv = rsqrtf(v + BN_EPS);
    float aa = bnw[tid] * inv;
    a[tid] = aa;
    sh[tid] = bnb[tid] - m * aa;
  }
  __syncthreads();
  for (int i = tid; i < CIN * COUT; i += 256) {
    int r = i / COUT;
    Wf[i] = a[r] * W[i];
  }
  if (tid < COUT) {
    float acc = bias ? bias[tid] : 0.f;
    for (int r = 0; r < CIN; ++r) acc += sh[r] * W[r * COUT + tid];
    bf[tid] = acc;
  }
}

// ---------------- out[N,64] = in[N,K] @ W[K,64] + bias (opt relu) ----------------
template <int K, bool RELU>
__global__ void k_nodemm(const float* __restrict__ in, int nrows,
                         const float* __restrict__ W, const float* __restrict__ bias,
                         float* __restrict__ out) {
  int tid = threadIdx.x;
  int lane = tid & 63;
  float w[K];
#pragma unroll
  for (int k = 0; k < K; ++k) w[k] = W[k * 64 + lane];
  float bv = bias ? bias[lane] : 0.f;
  int wave = (blockIdx.x * blockDim.x + tid) >> 6;
  int nwaves = (gridDim.x * blockDim.x) >> 6;
  for (int r = wave; r < nrows; r += nwaves) {
    float rv = (lane < K) ? in[r * K + lane] : 0.f;
    float acc = bv;
#pragma unroll
    for (int k = 0; k < K; ++k) acc = fmaf(bcast(rv, k), w[k], acc);
    if (RELU) acc = fmaxf(acc, 0.f);
    out[r * 64 + lane] = acc;
  }
}

// ---------------- e = relu(hA[src] + hB[dst] + ea@We0c) -> bf16 ----------------
__global__ void k_edgeinit(const float* __restrict__ hA, const float* __restrict__ hB,
                           const float* __restrict__ ea, const float* __restrict__ Wc,
                           const int* __restrict__ src, const int* __restrict__ dst,
                           __hip_bfloat16* __restrict__ ebf) {
  int tid = threadIdx.x;
  int lane = tid & 63;
  float w[FEDGE];
#pragma unroll
  for (int k = 0; k < FEDGE; ++k) w[k] = Wc[k * 64 + lane];
  int wave = (blockIdx.x * blockDim.x + tid) >> 6;
  int nwaves = (gridDim.x * blockDim.x) >> 6;
  for (int e = wave; e < N_EDGESC; e += nwaves) {
    int s = src[e], d = dst[e];
    float av = (lane < FEDGE) ? ea[e * FEDGE + lane] : 0.f;
    float acc = hA[s * 64 + lane] + hB[d * 64 + lane];
#pragma unroll
    for (int k = 0; k < FEDGE; ++k) acc = fmaf(bcast(av, k), w[k], acc);
    acc = fmaxf(acc, 0.f);
    ebf[(size_t)e * 64 + lane] = __float2bfloat16(acc);
  }
}

// ---------------- edge-gated conv: gate=htA[s]+htB[d]+e@We2; msg scatter ----------------
__global__ void k_conv(const __hip_bfloat16* __restrict__ ebf,
                       const float* __restrict__ We2,
                       const float* __restrict__ ht, const float* __restrict__ htA,
                       const float* __restrict__ htB, const float* __restrict__ dinv,
                       const int* __restrict__ src, const int* __restrict__ dst,
                       float* __restrict__ hacc) {
  int tid = threadIdx.x;
  int lane = tid & 63;
  float w[64];
#pragma unroll
  for (int k = 0; k < 64; ++k) w[k] = We2[k * 64 + lane];
  int wave = (blockIdx.x * blockDim.x + tid) >> 6;
  int nwaves = (gridDim.x * blockDim.x) >> 6;
  for (int e = wave; e < N_EDGESC; e += nwaves) {
    int s = src[e], d = dst[e];
    float ev = __bfloat162float(ebf[(size_t)e * 64 + lane]);
    float acc = htA[s * 64 + lane] + htB[d * 64 + lane];
#pragma unroll
    for (int k = 0; k < 64; ++k) acc = fmaf(bcast(ev, k), w[k], acc);
    float sig = 1.0f / (1.0f + __expf(-acc));
    float msg = dinv[s] * dinv[d] * ht[s * 64 + lane] * sig;
    atomicAdd(&hacc[d * 64 + lane], msg);
  }
}

// ---------------- h = relu(in), column stats of result ----------------
__global__ void k_relu_stats(const float* __restrict__ in, float* __restrict__ h,
                             float* __restrict__ stats, int nrows) {
  int tid = threadIdx.x;
  float s = 0.f, s2 = 0.f;
  int total = nrows * 64;
  for (int i = blockIdx.x * 256 + tid; i < total; i += gridDim.x * 256) {
    float v = fmaxf(in[i], 0.f);
    h[i] = v;
    s += v; s2 += v * v;
  }
  __shared__ float ls[256], ls2[256];
  ls[tid] = s; ls2[tid] = s2;
  __syncthreads();
  for (int off = 128; off >= 64; off >>= 1) {
    if (tid < off) { ls[tid] += ls[tid + off]; ls2[tid] += ls2[tid + off]; }
    __syncthreads();
  }
  if (tid < 64) {
    atomicAdd(&stats[tid], ls[tid]);
    atomicAdd(&stats[64 + tid], ls2[tid]);
  }
}

// ---------------- global_add_pool (batch is sorted) ----------------
__global__ void k_pool(const float* __restrict__ h, const int* __restrict__ batch,
                       float* __restrict__ g) {
  int lane = threadIdx.x & 63;
  int wave = (blockIdx.x * blockDim.x + threadIdx.x) >> 6;
  int nwaves = (gridDim.x * blockDim.x) >> 6;
  int chunk = (N_NODESC + nwaves - 1) / nwaves;
  int r0 = wave * chunk;
  int r1 = min(r0 + chunk, N_NODESC);
  if (r0 >= r1) return;
  int cur = batch[r0];
  float acc = 0.f;
  for (int r = r0; r < r1; ++r) {
    int b = batch[r];
    if (b != cur) {
      atomicAdd(&g[cur * 64 + lane], acc);
      acc = 0.f;
      cur = b;
    }
    acc += h[r * 64 + lane];
  }
  atomicAdd(&g[cur * 64 + lane], acc);
}

// ---------------- classifier + log_softmax ----------------
__global__ void k_cls(const float* __restrict__ g2, const float* __restrict__ Wc,
                      const float* __restrict__ bc, float* __restrict__ out) {
  int r = blockIdx.x * blockDim.x + threadIdx.x;
  if (r >= N_GRAPHSC) return;
  float z[NCLS];
#pragma unroll
  for (int c = 0; c < NCLS; ++c) z[c] = bc[c];
  for (int k = 0; k < HDIM; ++k) {
    float v = g2[r * HDIM + k];
#pragma unroll
    for (int c = 0; c < NCLS; ++c) z[c] = fmaf(v, Wc[k * NCLS + c], z[c]);
  }
  float m = z[0];
#pragma unroll
  for (int c = 1; c < NCLS; ++c) m = fmaxf(m, z[c]);
  float ssum = 0.f;
#pragma unroll
  for (int c = 0; c < NCLS; ++c) ssum += __expf(z[c] - m);
  float l = __logf(ssum);
#pragma unroll
  for (int c = 0; c < NCLS; ++c) out[r * NCLS + c] = z[c] - m - l;
}

extern "C" void kernel_launch(void* const* d_in, const int* in_sizes, int n_in,
                              void* d_out, int out_size, void* d_ws, size_t ws_size,
                              hipStream_t stream) {
  const float* x         = (const float*)d_in[0];
  const float* edge_attr = (const float*)d_in[1];
  const int*   ei        = (const int*)d_in[2];
  const int*   batch     = (const int*)d_in[3];
  const float* bn_feat_w = (const float*)d_in[4];
  const float* bn_feat_b = (const float*)d_in[5];
  const float* Wn0       = (const float*)d_in[6];
  const float* bn0       = (const float*)d_in[7];
  const float* We0       = (const float*)d_in[8];
  const float* be0       = (const float*)d_in[9];
  const float* bns_w     = (const float*)d_in[10];
  const float* bns_b     = (const float*)d_in[11];
  const float* Wn        = (const float*)d_in[12];
  const float* Wnb       = (const float*)d_in[13];
  const float* We        = (const float*)d_in[14];
  const float* Web       = (const float*)d_in[15];
  const float* bn_fc_w   = (const float*)d_in[16];
  const float* bn_fc_b   = (const float*)d_in[17];
  const float* Wfc       = (const float*)d_in[18];
  const float* bfc       = (const float*)d_in[19];
  const float* bn_hid_w  = (const float*)d_in[20];
  const float* bn_hid_b  = (const float*)d_in[21];
  const float* Wcls      = (const float*)d_in[22];
  const float* bcls      = (const float*)d_in[23];
  float* out = (float*)d_out;
  const int* src = ei;
  const int* dst = ei + N_EDGESC;

  char* p = (char*)d_ws;
  auto carve = [&](size_t bytes) {
    char* q = p;
    p += (bytes + 255) & ~(size_t)255;
    return q;
  };
  __hip_bfloat16* ebf = (__hip_bfloat16*)carve((size_t)N_EDGESC * 64 * 2);
  float* h    = (float*)carve((size_t)N_NODESC * 64 * 4);
  float* hA   = (float*)carve((size_t)N_NODESC * 64 * 4);
  float* hB   = (float*)carve((size_t)N_NODESC * 64 * 4);
  float* ht   = (float*)carve((size_t)N_NODESC * 64 * 4);
  float* hacc = (float*)carve((size_t)N_NODESC * 64 * 4);
  float* dinv = (float*)carve((size_t)N_NODESC * 4);
  float* g    = (float*)carve((size_t)N_GRAPHSC * 64 * 4);
  float* g2   = (float*)carve((size_t)N_GRAPHSC * 64 * 4);
  float* stats= (float*)carve(2 * 64 * 4);
  float* Wf   = (float*)carve(64 * 64 * 4);
  float* bf   = (float*)carve(64 * 4);

  // degree -> dinv
  hipMemsetAsync(dinv, 0, N_NODESC * 4, stream);
  k_deg<<<(N_EDGESC + 255) / 256, 256, 0, stream>>>(dst, dinv);
  k_dinv<<<(N_NODESC + 255) / 256, 256, 0, stream>>>(dinv);

  // h0 = BN(x)@Wn0 + bn0 (BN folded)
  hipMemsetAsync(stats, 0, 512, stream);
  k_colstats<FNODE><<<256, 256, 0, stream>>>(x, N_NODESC, stats);
  k_foldbn<FNODE, HDIM><<<1, 256, 0, stream>>>(stats, 1.f / N_NODESC, bn_feat_w, bn_feat_b, Wn0, bn0, Wf, bf);
  k_nodemm<FNODE, false><<<512, 256, 0, stream>>>(x, N_NODESC, Wf, bf, h);

  // hA = h0@We0A + be0, hB = h0@We0B ; e = relu(hA[src]+hB[dst]+ea@We0c)
  k_nodemm<HDIM, false><<<512, 256, 0, stream>>>(h, N_NODESC, We0, be0, hA);
  k_nodemm<HDIM, false><<<512, 256, 0, stream>>>(h, N_NODESC, We0 + 64 * 64, nullptr, hB);
  k_edgeinit<<<1024, 256, 0, stream>>>(hA, hB, edge_attr, We0 + 128 * 64, src, dst, ebf);

  // h = relu(h0), stats(h)
  hipMemsetAsync(stats, 0, 512, stream);
  k_relu_stats<<<256, 256, 0, stream>>>(h, h, stats, N_NODESC);

  for (int i = 0; i < 3; ++i) {
    const float* WeI = We + (size_t)i * 192 * 64;
    k_foldbn<HDIM, HDIM><<<1, 256, 0, stream>>>(stats, 1.f / N_NODESC, bns_w + i * 64, bns_b + i * 64,
                                                Wn + (size_t)i * 64 * 64, Wnb + i * 64, Wf, bf);
    k_nodemm<HDIM, false><<<512, 256, 0, stream>>>(h, N_NODESC, Wf, bf, ht);
    k_nodemm<HDIM, false><<<512, 256, 0, stream>>>(ht, N_NODESC, WeI, Web + i * 64, hA);       // htA (+Web)
    k_nodemm<HDIM, false><<<512, 256, 0, stream>>>(ht, N_NODESC, WeI + 64 * 64, nullptr, hB);  // htB
    hipMemsetAsync(hacc, 0, (size_t)N_NODESC * 64 * 4, stream);
    k_conv<<<2048, 256, 0, stream>>>(ebf, WeI + 128 * 64, ht, hA, hB, dinv, src, dst, hacc);
    hipMemsetAsync(stats, 0, 512, stream);
    k_relu_stats<<<256, 256, 0, stream>>>(hacc, h, stats, N_NODESC);
  }

  // pool + head
  hipMemsetAsync(g, 0, N_GRAPHSC * 64 * 4, stream);
  k_pool<<<64, 256, 0, stream>>>(h, batch, g);
  hipMemsetAsync(stats, 0, 512, stream);
  k_colstats<HDIM><<<32, 256, 0, stream>>>(g, N_GRAPHSC, stats);
  k_foldbn<HDIM, HDIM><<<1, 256, 0, stream>>>(stats, 1.f / N_GRAPHSC, bn_fc_w, bn_fc_b, Wfc, bfc, Wf, bf);
  k_nodemm<HDIM, true><<<128, 256, 0, stream>>>(g, N_GRAPHSC, Wf, bf, g2);
  hipMemsetAsync(stats, 0, 512, stream);
  k_colstats<HDIM><<<32, 256, 0, stream>>>(g2, N_GRAPHSC, stats);
  k_foldbn<HDIM, NCLS><<<1, 256, 0, stream>>>(stats, 1.f / N_GRAPHSC, bn_hid_w, bn_hid_b, Wcls, bcls, Wf, bf);
  k_cls<<<(N_GRAPHSC + 255) / 256, 256, 0, stream>>>(g2, Wf, bf, out);
}

// Round 2
// 1171.922 us; speedup vs baseline: 1.2370x; 1.2370x over previous
//
#include <hip/hip_runtime.h>
#include <hip/hip_bf16.h>

#define N_NODESC 50000
#define N_EDGESC 800000
#define N_GRAPHSC 512
#define HDIM 64
#define FNODE 32
#define FEDGE 8
#define NCLS 10
#define BN_EPS 1e-5f

typedef __bf16 bf16x8 __attribute__((ext_vector_type(8)));
typedef float f32x4 __attribute__((ext_vector_type(4)));

static __device__ __forceinline__ float bcast(float v, int k) {
  return __uint_as_float(__builtin_amdgcn_readlane(__float_as_uint(v), k));
}

// ---------------- degree / norm ----------------
__global__ void k_deg(const int* __restrict__ dst, float* __restrict__ deg) {
  int e = blockIdx.x * blockDim.x + threadIdx.x;
  if (e < N_EDGESC) atomicAdd(&deg[dst[e]], 1.0f);
}

__global__ void k_dinv(float* __restrict__ deg) {
  int n = blockIdx.x * blockDim.x + threadIdx.x;
  if (n < N_NODESC) {
    float d = deg[n];
    deg[n] = rsqrtf(fmaxf(d, 1.0f));
  }
}

// ---------------- column stats (sum, sumsq) ----------------
template <int C>
__global__ void k_colstats(const float* __restrict__ in, int nrows, float* __restrict__ stats) {
  const int RPB = 256 / C;
  int tid = threadIdx.x;
  int col = tid % C;
  int rowOff = tid / C;
  float s = 0.f, s2 = 0.f;
  for (int r = blockIdx.x * RPB + rowOff; r < nrows; r += gridDim.x * RPB) {
    float v = in[r * C + col];
    s += v; s2 += v * v;
  }
  __shared__ float ls[256], ls2[256];
  ls[tid] = s; ls2[tid] = s2;
  __syncthreads();
  for (int off = 128; off >= C; off >>= 1) {
    if (tid < off) { ls[tid] += ls[tid + off]; ls2[tid] += ls2[tid + off]; }
    __syncthreads();
  }
  if (tid < C) {
    atomicAdd(&stats[tid], ls[tid]);
    atomicAdd(&stats[C + tid], ls2[tid]);
  }
}

// ---------------- fold BN into weights: Wf = a.*W, bf = sh@W + bias ----------------
template <int CIN, int COUT>
__global__ void k_foldbn(const float* __restrict__ stats, float invN,
                         const float* __restrict__ bnw, const float* __restrict__ bnb,
                         const float* __restrict__ W, const float* __restrict__ bias,
                         float* __restrict__ Wf, float* __restrict__ bf) {
  __shared__ float a[CIN], sh[CIN];
  int tid = threadIdx.x;
  if (tid < CIN) {
    float m = stats[tid] * invN;
    float v = stats[CIN + tid] * invN - m * m;
    float inv = rsqrtf(v + BN_EPS);
    float aa = bnw[tid] * inv;
    a[tid] = aa;
    sh[tid] = bnb[tid] - m * aa;
  }
  __syncthreads();
  for (int i = tid; i < CIN * COUT; i += 256) {
    int r = i / COUT;
    Wf[i] = a[r] * W[i];
  }
  if (tid < COUT) {
    float acc = bias ? bias[tid] : 0.f;
    for (int r = 0; r < CIN; ++r) acc += sh[r] * W[r * COUT + tid];
    bf[tid] = acc;
  }
}

// ---------------- out[N,64] = in[N,K] @ W[K,64] + bias (opt relu) ----------------
template <int K, bool RELU>
__global__ void k_nodemm(const float* __restrict__ in, int nrows,
                         const float* __restrict__ W, const float* __restrict__ bias,
                         float* __restrict__ out) {
  int tid = threadIdx.x;
  int lane = tid & 63;
  float w[K];
#pragma unroll
  for (int k = 0; k < K; ++k) w[k] = W[k * 64 + lane];
  float bv = bias ? bias[lane] : 0.f;
  int wave = (blockIdx.x * blockDim.x + tid) >> 6;
  int nwaves = (gridDim.x * blockDim.x) >> 6;
  for (int r = wave; r < nrows; r += nwaves) {
    float rv = (lane < K) ? in[r * K + lane] : 0.f;
    float acc = bv;
#pragma unroll
    for (int k = 0; k < K; ++k) acc = fmaf(bcast(rv, k), w[k], acc);
    if (RELU) acc = fmaxf(acc, 0.f);
    out[r * 64 + lane] = acc;
  }
}

// ---------------- e = relu(hA[src] + hB[dst] + ea@We0c) -> bf16 ----------------
__global__ void k_edgeinit(const float* __restrict__ hA, const float* __restrict__ hB,
                           const float* __restrict__ ea, const float* __restrict__ Wc,
                           const int* __restrict__ src, const int* __restrict__ dst,
                           __hip_bfloat16* __restrict__ ebf) {
  int tid = threadIdx.x;
  int lane = tid & 63;
  float w[FEDGE];
#pragma unroll
  for (int k = 0; k < FEDGE; ++k) w[k] = Wc[k * 64 + lane];
  int wave = (blockIdx.x * blockDim.x + tid) >> 6;
  int nwaves = (gridDim.x * blockDim.x) >> 6;
  for (int e = wave; e < N_EDGESC; e += nwaves) {
    int s = src[e], d = dst[e];
    float av = (lane < FEDGE) ? ea[e * FEDGE + lane] : 0.f;
    float acc = hA[s * 64 + lane] + hB[d * 64 + lane];
#pragma unroll
    for (int k = 0; k < FEDGE; ++k) acc = fmaf(bcast(av, k), w[k], acc);
    acc = fmaxf(acc, 0.f);
    ebf[(size_t)e * 64 + lane] = __float2bfloat16(acc);
  }
}

// ---------------- edge-gated conv with MFMA gate GEMM ----------------
// gate = e@We2 + htA[src] + htB[dst]; msg = dinv[s]*dinv[d]*ht[src]*sigmoid(gate)
// A = e-tile [16 edges x 64], B = We2 [64 x 64] (bf16 frags held in VGPRs).
__global__ void __launch_bounds__(256) k_conv_mfma(
    const __hip_bfloat16* __restrict__ ebf,
    const float* __restrict__ We2,
    const float* __restrict__ ht, const float* __restrict__ htA,
    const float* __restrict__ htB, const float* __restrict__ dinv,
    const int* __restrict__ src, const int* __restrict__ dst,
    float* __restrict__ hacc) {
  const int lane = threadIdx.x & 63;
  const int m  = lane & 15;   // A-row / B-col / D-col within 16-tile
  const int kg = lane >> 4;   // k-group (8 k's each)

  // B fragments: b[t][s] -> B[k = s*32 + kg*8 + j][c = t*16 + m]
  bf16x8 b[4][2];
#pragma unroll
  for (int t = 0; t < 4; ++t)
#pragma unroll
    for (int s = 0; s < 2; ++s)
#pragma unroll
      for (int j = 0; j < 8; ++j) {
        int k = s * 32 + kg * 8 + j;
        int c = t * 16 + m;
        b[t][s][j] = (__bf16)We2[k * 64 + c];
      }

  int wave = (blockIdx.x * blockDim.x + threadIdx.x) >> 6;
  int nwaves = (gridDim.x * blockDim.x) >> 6;
  const int ntiles = N_EDGESC / 16;
  for (int tile = wave; tile < ntiles; tile += nwaves) {
    int base = tile * 16;
    const __hip_bfloat16* arow = ebf + (size_t)(base + m) * 64 + kg * 8;
    bf16x8 a0 = *reinterpret_cast<const bf16x8*>(arow);
    bf16x8 a1 = *reinterpret_cast<const bf16x8*>(arow + 32);
    f32x4 acc[4];
#pragma unroll
    for (int t = 0; t < 4; ++t) {
      f32x4 z = {0.f, 0.f, 0.f, 0.f};
      acc[t] = __builtin_amdgcn_mfma_f32_16x16x32_bf16(a0, b[t][0], z, 0, 0, 0);
      acc[t] = __builtin_amdgcn_mfma_f32_16x16x32_bf16(a1, b[t][1], acc[t], 0, 0, 0);
    }
    // D mapping: lane holds col c = t*16+m, rows r = kg*4 + j
    int rbase = base + kg * 4;
#pragma unroll
    for (int j = 0; j < 4; ++j) {
      int er = rbase + j;
      int s = src[er], d = dst[er];
      float nrm = dinv[s] * dinv[d];
#pragma unroll
      for (int t = 0; t < 4; ++t) {
        int c = t * 16 + m;
        float gate = acc[t][j] + htA[s * 64 + c] + htB[d * 64 + c];
        float sig = 1.0f / (1.0f + __expf(-gate));
        float msg = nrm * ht[s * 64 + c] * sig;
        atomicAdd(&hacc[d * 64 + c], msg);
      }
    }
  }
}

// ---------------- h = relu(in), column stats of result ----------------
__global__ void k_relu_stats(const float* __restrict__ in, float* __restrict__ h,
                             float* __restrict__ stats, int nrows) {
  int tid = threadIdx.x;
  float s = 0.f, s2 = 0.f;
  int total = nrows * 64;
  for (int i = blockIdx.x * 256 + tid; i < total; i += gridDim.x * 256) {
    float v = fmaxf(in[i], 0.f);
    h[i] = v;
    s += v; s2 += v * v;
  }
  __shared__ float ls[256], ls2[256];
  ls[tid] = s; ls2[tid] = s2;
  __syncthreads();
  for (int off = 128; off >= 64; off >>= 1) {
    if (tid < off) { ls[tid] += ls[tid + off]; ls2[tid] += ls2[tid + off]; }
    __syncthreads();
  }
  if (tid < 64) {
    atomicAdd(&stats[tid], ls[tid]);
    atomicAdd(&stats[64 + tid], ls2[tid]);
  }
}

// ---------------- global_add_pool (batch is sorted) ----------------
__global__ void k_pool(const float* __restrict__ h, const int* __restrict__ batch,
                       float* __restrict__ g) {
  int lane = threadIdx.x & 63;
  int wave = (blockIdx.x * blockDim.x + threadIdx.x) >> 6;
  int nwaves = (gridDim.x * blockDim.x) >> 6;
  int chunk = (N_NODESC + nwaves - 1) / nwaves;
  int r0 = wave * chunk;
  int r1 = min(r0 + chunk, N_NODESC);
  if (r0 >= r1) return;
  int cur = batch[r0];
  float acc = 0.f;
  for (int r = r0; r < r1; ++r) {
    int b = batch[r];
    if (b != cur) {
      atomicAdd(&g[cur * 64 + lane], acc);
      acc = 0.f;
      cur = b;
    }
    acc += h[r * 64 + lane];
  }
  atomicAdd(&g[cur * 64 + lane], acc);
}

// ---------------- classifier + log_softmax ----------------
__global__ void k_cls(const float* __restrict__ g2, const float* __restrict__ Wc,
                      const float* __restrict__ bc, float* __restrict__ out) {
  int r = blockIdx.x * blockDim.x + threadIdx.x;
  if (r >= N_GRAPHSC) return;
  float z[NCLS];
#pragma unroll
  for (int c = 0; c < NCLS; ++c) z[c] = bc[c];
  for (int k = 0; k < HDIM; ++k) {
    float v = g2[r * HDIM + k];
#pragma unroll
    for (int c = 0; c < NCLS; ++c) z[c] = fmaf(v, Wc[k * NCLS + c], z[c]);
  }
  float m = z[0];
#pragma unroll
  for (int c = 1; c < NCLS; ++c) m = fmaxf(m, z[c]);
  float ssum = 0.f;
#pragma unroll
  for (int c = 0; c < NCLS; ++c) ssum += __expf(z[c] - m);
  float l = __logf(ssum);
#pragma unroll
  for (int c = 0; c < NCLS; ++c) out[r * NCLS + c] = z[c] - m - l;
}

extern "C" void kernel_launch(void* const* d_in, const int* in_sizes, int n_in,
                              void* d_out, int out_size, void* d_ws, size_t ws_size,
                              hipStream_t stream) {
  const float* x         = (const float*)d_in[0];
  const float* edge_attr = (const float*)d_in[1];
  const int*   ei        = (const int*)d_in[2];
  const int*   batch     = (const int*)d_in[3];
  const float* bn_feat_w = (const float*)d_in[4];
  const float* bn_feat_b = (const float*)d_in[5];
  const float* Wn0       = (const float*)d_in[6];
  const float* bn0       = (const float*)d_in[7];
  const float* We0       = (const float*)d_in[8];
  const float* be0       = (const float*)d_in[9];
  const float* bns_w     = (const float*)d_in[10];
  const float* bns_b     = (const float*)d_in[11];
  const float* Wn        = (const float*)d_in[12];
  const float* Wnb       = (const float*)d_in[13];
  const float* We        = (const float*)d_in[14];
  const float* Web       = (const float*)d_in[15];
  const float* bn_fc_w   = (const float*)d_in[16];
  const float* bn_fc_b   = (const float*)d_in[17];
  const float* Wfc       = (const float*)d_in[18];
  const float* bfc       = (const float*)d_in[19];
  const float* bn_hid_w  = (const float*)d_in[20];
  const float* bn_hid_b  = (const float*)d_in[21];
  const float* Wcls      = (const float*)d_in[22];
  const float* bcls      = (const float*)d_in[23];
  float* out = (float*)d_out;
  const int* src = ei;
  const int* dst = ei + N_EDGESC;

  char* p = (char*)d_ws;
  auto carve = [&](size_t bytes) {
    char* q = p;
    p += (bytes + 255) & ~(size_t)255;
    return q;
  };
  __hip_bfloat16* ebf = (__hip_bfloat16*)carve((size_t)N_EDGESC * 64 * 2);
  float* h    = (float*)carve((size_t)N_NODESC * 64 * 4);
  float* hA   = (float*)carve((size_t)N_NODESC * 64 * 4);
  float* hB   = (float*)carve((size_t)N_NODESC * 64 * 4);
  float* ht   = (float*)carve((size_t)N_NODESC * 64 * 4);
  float* hacc = (float*)carve((size_t)N_NODESC * 64 * 4);
  float* dinv = (float*)carve((size_t)N_NODESC * 4);
  float* g    = (float*)carve((size_t)N_GRAPHSC * 64 * 4);
  float* g2   = (float*)carve((size_t)N_GRAPHSC * 64 * 4);
  float* stats= (float*)carve(2 * 64 * 4);
  float* Wf   = (float*)carve(64 * 64 * 4);
  float* bf   = (float*)carve(64 * 4);

  // degree -> dinv
  hipMemsetAsync(dinv, 0, N_NODESC * 4, stream);
  k_deg<<<(N_EDGESC + 255) / 256, 256, 0, stream>>>(dst, dinv);
  k_dinv<<<(N_NODESC + 255) / 256, 256, 0, stream>>>(dinv);

  // h0 = BN(x)@Wn0 + bn0 (BN folded)
  hipMemsetAsync(stats, 0, 512, stream);
  k_colstats<FNODE><<<256, 256, 0, stream>>>(x, N_NODESC, stats);
  k_foldbn<FNODE, HDIM><<<1, 256, 0, stream>>>(stats, 1.f / N_NODESC, bn_feat_w, bn_feat_b, Wn0, bn0, Wf, bf);
  k_nodemm<FNODE, false><<<512, 256, 0, stream>>>(x, N_NODESC, Wf, bf, h);

  // hA = h0@We0A + be0, hB = h0@We0B ; e = relu(hA[src]+hB[dst]+ea@We0c)
  k_nodemm<HDIM, false><<<512, 256, 0, stream>>>(h, N_NODESC, We0, be0, hA);
  k_nodemm<HDIM, false><<<512, 256, 0, stream>>>(h, N_NODESC, We0 + 64 * 64, nullptr, hB);
  k_edgeinit<<<1024, 256, 0, stream>>>(hA, hB, edge_attr, We0 + 128 * 64, src, dst, ebf);

  // h = relu(h0), stats(h)
  hipMemsetAsync(stats, 0, 512, stream);
  k_relu_stats<<<256, 256, 0, stream>>>(h, h, stats, N_NODESC);

  for (int i = 0; i < 3; ++i) {
    const float* WeI = We + (size_t)i * 192 * 64;
    k_foldbn<HDIM, HDIM><<<1, 256, 0, stream>>>(stats, 1.f / N_NODESC, bns_w + i * 64, bns_b + i * 64,
                                                Wn + (size_t)i * 64 * 64, Wnb + i * 64, Wf, bf);
    k_nodemm<HDIM, false><<<512, 256, 0, stream>>>(h, N_NODESC, Wf, bf, ht);
    k_nodemm<HDIM, false><<<512, 256, 0, stream>>>(ht, N_NODESC, WeI, Web + i * 64, hA);       // htA (+Web)
    k_nodemm<HDIM, false><<<512, 256, 0, stream>>>(ht, N_NODESC, WeI + 64 * 64, nullptr, hB);  // htB
    hipMemsetAsync(hacc, 0, (size_t)N_NODESC * 64 * 4, stream);
    k_conv_mfma<<<2048, 256, 0, stream>>>(ebf, WeI + 128 * 64, ht, hA, hB, dinv, src, dst, hacc);
    hipMemsetAsync(stats, 0, 512, stream);
    k_relu_stats<<<256, 256, 0, stream>>>(hacc, h, stats, N_NODESC);
  }

  // pool + head
  hipMemsetAsync(g, 0, N_GRAPHSC * 64 * 4, stream);
  k_pool<<<64, 256, 0, stream>>>(h, batch, g);
  hipMemsetAsync(stats, 0, 512, stream);
  k_colstats<HDIM><<<32, 256, 0, stream>>>(g, N_GRAPHSC, stats);
  k_foldbn<HDIM, HDIM><<<1, 256, 0, stream>>>(stats, 1.f / N_GRAPHSC, bn_fc_w, bn_fc_b, Wfc, bfc, Wf, bf);
  k_nodemm<HDIM, true><<<128, 256, 0, stream>>>(g, N_GRAPHSC, Wf, bf, g2);
  hipMemsetAsync(stats, 0, 512, stream);
  k_colstats<HDIM><<<32, 256, 0, stream>>>(g2, N_GRAPHSC, stats);
  k_foldbn<HDIM, NCLS><<<1, 256, 0, stream>>>(stats, 1.f / N_GRAPHSC, bn_hid_w, bn_hid_b, Wcls, bcls, Wf, bf);
  k_cls<<<(N_GRAPHSC + 255) / 256, 256, 0, stream>>>(g2, Wf, bf, out);
}